// Round 1
// baseline (155.735 us; speedup 1.0000x reference)
//
#include <hip/hip_runtime.h>

#define BB 256
#define LL 512
#define TT 128
#define CH 16  // staged steps per chunk

typedef _Float16 h2 __attribute__((ext_vector_type(2)));

#if defined(__has_builtin)
#if __has_builtin(__builtin_amdgcn_fdot2)
#define FDOT2(a, b, c) __builtin_amdgcn_fdot2((a), (b), (c), false)
#endif
#endif
#ifndef FDOT2
static __device__ inline float fdot2_fb(h2 a, h2 b, float c) {
  return fmaf((float)a.x, (float)b.x, fmaf((float)a.y, (float)b.y, c));
}
#define FDOT2(a, b, c) fdot2_fb((a), (b), (c))
#endif

// Full-wave max via DPP (VALU pipe only — off the LDS queue).
static __device__ inline float wave_max_dpp(float x) {
  int v = __float_as_int(x);
#define DPP_STEP(ctrl)                                                  \
  {                                                                     \
    int t = __builtin_amdgcn_update_dpp(v, v, (ctrl), 0xf, 0xf, false); \
    x = fmaxf(x, __int_as_float(t));                                    \
    v = __float_as_int(x);                                              \
  }
  DPP_STEP(0x111) DPP_STEP(0x112) DPP_STEP(0x114) DPP_STEP(0x118)
  DPP_STEP(0x142) DPP_STEP(0x143)
#undef DPP_STEP
  return __int_as_float(__builtin_amdgcn_readlane(v, 63));
}

// Raw workgroup barrier: drain own LDS ops then s_barrier. Avoids the
// vmcnt(0) drain __syncthreads() imposes (would stall on in-flight
// emission staging loads every step). "memory" clobber pins all LDS /
// global ops on their side of the barrier.
static __device__ inline void wg_bar() {
  asm volatile("s_waitcnt lgkmcnt(0)\n\ts_barrier" ::: "memory");
}

static __device__ inline h2 bch2(unsigned u) { return __builtin_bit_cast(h2, u); }
static __device__ inline unsigned expbits(unsigned u) {
  return __float_as_uint(__expf(__uint_as_float(u)));
}

// Blocks [0,BB): chains. One block per batch; 4 chain waves:
//   wid0/1 = forward halves (output cols 0..63 / 64..127)
//   wid2/3 = backward halves (output rows 0..63 / 64..127)
// Per step each wave does 64 dot2 (vs 128 before), with a raw barrier and
// parity-double-buffered state (ef/gb[2]) + scale slots so there is no
// read/write race between the two halves. Emission exp() is folded at
// staging time (register-staged, T14 style). Scale = exact pow2
// bookkeeping identical to the verified kernel.
// Blocks [BB,2*BB): numerator for batch (blockIdx - BB), runs concurrently.
__global__ __launch_bounds__(256)
__attribute__((amdgpu_waves_per_eu(1, 2)))
void crf_main(const float* __restrict__ inputs, const float* __restrict__ trans,
              const float* __restrict__ start_t, const float* __restrict__ end_t,
              const int* __restrict__ tags, const int* __restrict__ mask,
              float* __restrict__ den, float* __restrict__ num) {
  const int tid = threadIdx.x;
  const int lane = tid & 63;
  const int wid = tid >> 6;

  __shared__ __align__(16) float fbuf[2][CH * TT];
  __shared__ __align__(16) float bbuf[2][CH * TT];
  __shared__ __align__(16) h2 ef[2][64];             // fwd state, by parity
  __shared__ __align__(16) h2 gb[2][64];             // bwd state, by parity
  __shared__ __align__(16) float mslot[2][2][2];     // [parity][dir][half]
  __shared__ float npart[4];
  __shared__ int sb_sh;

  if (blockIdx.x >= BB) {
    // ---------------- numerator ----------------
    const int b = blockIdx.x - BB;
    int lm = 0;
    const int* mk = mask + b * LL;
#pragma unroll
    for (int q = 0; q < LL / 64; ++q) lm += mk[q * 64 + lane];
#pragma unroll
    for (int d = 1; d < 64; d <<= 1) lm += __shfl_xor(lm, d);
    const int len = lm;
    const int* tg = tags + (size_t)b * LL;
    const float* erow = inputs + (size_t)b * LL * TT;
    const int lo = (wid * len) >> 2, hi = ((wid + 1) * len) >> 2;
    float sc = 0.f;
    for (int t = lo + lane; t < hi; t += 64) {
      int cu = tg[t];
      sc += erow[(size_t)t * TT + cu];
      if (t >= 1) sc += trans[tg[t - 1] * TT + cu];
    }
#pragma unroll
    for (int d = 1; d < 64; d <<= 1) sc += __shfl_xor(sc, d);
    if (lane == 0) npart[wid] = sc;
    __syncthreads();
    if (tid == 0)
      num[b] = npart[0] + npart[1] + npart[2] + npart[3] + start_t[tg[0]] +
               end_t[tg[len - 1]];
    return;
  }

  // ---------------- forward/backward chains ----------------
  const int b = blockIdx.x;
  const int dir = wid >> 1;      // 0 = forward, 1 = backward
  const int hw = wid & 1;        // which half of the 128 outputs
  const int j = hw * 64 + lane;  // output state index (fwd col / bwd row)

  int lm = 0;
  const int* mk = mask + b * LL;
#pragma unroll
  for (int q = 0; q < LL / 64; ++q) lm += mk[q * 64 + lane];
#pragma unroll
  for (int d = 1; d < 64; d <<= 1) lm += __shfl_xor(lm, d);
  const int len = lm;               // [256, 512]
  const int m = (len - 1) >> 1;     // meeting point (>=127)
  const int K = len - 1 - m;        // bwd step count; fwd does m (= K or K-1)
  const int NC = (K + CH - 1) / CH;

  const float* erow = inputs + (size_t)b * LL * TT;

  uint4 st0, st1, st2, st3;  // register-staged emission rows (8 rows/wave)
  auto STLD = [&](const float* gbase) {
    const uint4* gs = (const uint4*)gbase;
    st0 = gs[0 * 64 + lane];
    st1 = gs[1 * 64 + lane];
    st2 = gs[2 * 64 + lane];
    st3 = gs[3 * 64 + lane];
  };
  auto STWR = [&](float* dstb) {  // exp() folded at staging time
    uint4* dst = (uint4*)(dstb + 8 * hw * TT);
    uint4 o;
    o.x = expbits(st0.x); o.y = expbits(st0.y); o.z = expbits(st0.z); o.w = expbits(st0.w);
    dst[0 * 64 + lane] = o;
    o.x = expbits(st1.x); o.y = expbits(st1.y); o.z = expbits(st1.z); o.w = expbits(st1.w);
    dst[1 * 64 + lane] = o;
    o.x = expbits(st2.x); o.y = expbits(st2.y); o.z = expbits(st2.z); o.w = expbits(st2.w);
    dst[2 * 64 + lane] = o;
    o.x = expbits(st3.x); o.y = expbits(st3.y); o.z = expbits(st3.z); o.w = expbits(st3.w);
    dst[3 * 64 + lane] = o;
  };

  // chunk-0 emission loads; latency hidden under the E preload
  if (dir == 0) STLD(erow + (size_t)(1 + 8 * hw) * TT);
  else          STLD(erow + (size_t)(len - 1 - CH + 8 * hw) * TT);

  // E fragment: fwd lane holds exp(trans[:, j]) as row-pairs (64 h2);
  // bwd lane holds exp(trans[j, :]) as col-pairs.
  h2 E[64];
  if (dir == 0) {
#pragma unroll
    for (int p = 0; p < 64; ++p) {
      float t0 = trans[(2 * p) * TT + j];
      float t1 = trans[(2 * p + 1) * TT + j];
      h2 e;
      e.x = (_Float16)__expf(t0);
      e.y = (_Float16)__expf(t1);
      E[p] = e;
    }
  } else {
    const float2* tr2 = (const float2*)trans;
#pragma unroll
    for (int p = 0; p < 64; ++p) {
      float2 r = tr2[j * 64 + p];
      h2 e;
      e.x = (_Float16)__expf(r.x);
      e.y = (_Float16)__expf(r.y);
      E[p] = e;
    }
  }

  // stage chunk 0
  STWR(dir == 0 ? fbuf[0] : bbuf[0]);

  // initial states + scale slots (parity 0)
  int S = 0;
  if (dir == 0) {
    float f = __expf(start_t[j] + erow[j]);
    ((_Float16*)ef[0])[j] = (_Float16)f;
    float mx = wave_max_dpp(f);
    if (lane == 0) mslot[0][0][hw] = mx;
  } else {
    float gv = __expf(end_t[j] + erow[(size_t)(len - 1) * TT + j]);
    ((_Float16*)gb[0])[j] = (_Float16)gv;
    float mx = wave_max_dpp(gv);
    if (lane == 0) mslot[0][1][hw] = mx;
  }
  wg_bar();

  auto DOTS = [&](const uint4* ep) -> float {
    float a0 = 0.f, a1 = 0.f, a2 = 0.f, a3 = 0.f;
#pragma unroll
    for (int r = 0; r < 16; ++r) {
      uint4 q = ep[r];  // broadcast read of full 128-state vector
      a0 = FDOT2(bch2(q.x), E[4 * r + 0], a0);
      a1 = FDOT2(bch2(q.y), E[4 * r + 1], a1);
      a2 = FDOT2(bch2(q.z), E[4 * r + 2], a2);
      a3 = FDOT2(bch2(q.w), E[4 * r + 3], a3);
    }
    return (a0 + a1) + (a2 + a3);
  };

  for (int c = 0; c < NC; ++c) {
    // issue next chunk's emission loads (consumed at chunk end)
    if (c + 1 < NC) {
      if (dir == 0) STLD(erow + (size_t)(1 + CH * (c + 1) + 8 * hw) * TT);
      else          STLD(erow + (size_t)(len - 1 - CH * (c + 2) + 8 * hw) * TT);
    }
    const int kend = min(CH * (c + 1), K);
    const float* __restrict__ fb = fbuf[c & 1];
    const float* __restrict__ bbm = bbuf[c & 1];
#pragma unroll 1
    for (int k = CH * c + 1; k <= kend; ++k) {
      const int pr = (k - 1) & 1, pw = k & 1;
      if (dir == 0) {
        if (k <= m) {  // fwd idles at most once (k==K when len even)
          float2 ms = *(const float2*)&mslot[pr][0][0];
          float mx = fmaxf(ms.x, ms.y);
          int exm = (int)((__float_as_uint(mx) >> 23) & 255) - 127;
          float inv_sc = __uint_as_float((unsigned)(120 - exm) << 23);
          S += exm + 7;
          float v = DOTS((const uint4*)ef[pr]);
          float femb = fb[(k - 1 - CH * c) * TT + j];  // exp already folded
          float w = v * (femb * inv_sc);
          ((_Float16*)ef[pw])[j] = (_Float16)w;
          float wm = wave_max_dpp(w);
          if (lane == 0) mslot[pw][0][hw] = wm;
        }
      } else {
        float2 ms = *(const float2*)&mslot[pr][1][0];
        float mx = fmaxf(ms.x, ms.y);
        int exm = (int)((__float_as_uint(mx) >> 23) & 255) - 127;
        float inv_sc = __uint_as_float((unsigned)(120 - exm) << 23);
        S += exm + 7;
        float v = DOTS((const uint4*)gb[pr]);
        float pex = bbm[(CH * (c + 1) - k) * TT + j];
        if (len - 1 - k > m) v *= pex;  // at t==m store without emission
        float w = v * inv_sc;
        ((_Float16*)gb[pw])[j] = (_Float16)w;
        float wm = wave_max_dpp(w);
        if (lane == 0) mslot[pw][1][hw] = wm;
      }
      wg_bar();
    }
    if (c + 1 < NC) {
      STWR(dir == 0 ? fbuf[(c + 1) & 1] : bbuf[(c + 1) & 1]);
      wg_bar();
    }
  }

  if (wid == 2 && lane == 0) sb_sh = S;
  wg_bar();

  if (wid == 0) {
    const int pf = m & 1, pb = K & 1;
    h2 a = ef[pf][lane];
    h2 gg = gb[pb][lane];
    float v = (float)a.x * (float)gg.x + (float)a.y * (float)gg.y;
#pragma unroll
    for (int d = 1; d < 64; d <<= 1) v += __shfl_xor(v, d);
    if (lane == 0)
      den[b] = (float)(S + sb_sh) * 0.6931471805599453f + __logf(v);
  }
}

// Deterministic final reduction: out = sum_b (num[b] - den[b]).
__global__ void crf_sum_kernel(const float* __restrict__ den,
                               const float* __restrict__ num,
                               float* __restrict__ out) {
  const int tid = threadIdx.x;  // 256
  float v = num[tid] - den[tid];
#pragma unroll
  for (int d = 1; d < 64; d <<= 1) v += __shfl_xor(v, d);
  __shared__ float r[4];
  if ((tid & 63) == 0) r[tid >> 6] = v;
  __syncthreads();
  if (tid == 0) out[0] = r[0] + r[1] + r[2] + r[3];
}

extern "C" void kernel_launch(void* const* d_in, const int* in_sizes, int n_in,
                              void* d_out, int out_size, void* d_ws, size_t ws_size,
                              hipStream_t stream) {
  const float* inputs = (const float*)d_in[0];
  const float* trans = (const float*)d_in[1];
  const float* start_t = (const float*)d_in[2];
  const float* end_t = (const float*)d_in[3];
  const int* tags = (const int*)d_in[4];
  const int* mask = (const int*)d_in[5];
  float* den = (float*)d_ws;   // 256 floats
  float* num = den + BB;       // 256 floats
  float* out = (float*)d_out;

  crf_main<<<2 * BB, 256, 0, stream>>>(inputs, trans, start_t, end_t, tags,
                                       mask, den, num);
  crf_sum_kernel<<<1, 256, 0, stream>>>(den, num, out);
}